// Round 1
// baseline (1334.196 us; speedup 1.0000x reference)
//
#include <hip/hip_runtime.h>
#include <hip/hip_bf16.h>
#include <cstdint>
#include <cstddef>

typedef __bf16 bf16x8 __attribute__((ext_vector_type(8)));
typedef __bf16 bf16x4 __attribute__((ext_vector_type(4)));
typedef float f32x4 __attribute__((ext_vector_type(4)));

constexpr int kN = 16384;   // nodes
constexpr int kD = 64;      // feature dim

// ---------------------------------------------------------------------------
// Kernel A (UNCHANGED, layout-verified): T = X @ W_agg, stored bf16,
// pre-swizzled into MFMA 16x16x32 B-fragment order:
//   vec-slot ((kb*4 + nb)*4 + kq)*16 + ln  (kb=k>>5, kq=(k>>3)&3, nb=n>>4, ln=n&15)
// ---------------------------------------------------------------------------
__global__ __launch_bounds__(256) void xw_swizzle_kernel(
    const float* __restrict__ X, const float* __restrict__ W,
    __bf16* __restrict__ Tsw) {
  __shared__ float Ws[kD * kD];
  const int tid = threadIdx.x;
#pragma unroll
  for (int i = 0; i < 16; ++i) Ws[i * 256 + tid] = W[i * 256 + tid];
  __syncthreads();

  const int t = blockIdx.x * 256 + tid;
  const int n = t & 63;            // output column
  const int kbase = (t >> 6) << 3; // first of 8 output rows (k of T)

  float acc[8];
#pragma unroll
  for (int i = 0; i < 8; ++i) acc[i] = 0.f;

  const f32x4* X4 = (const f32x4*)X;
#pragma unroll 4
  for (int d4 = 0; d4 < 16; ++d4) {
    const float w0 = Ws[(d4 * 4 + 0) * 64 + n];
    const float w1 = Ws[(d4 * 4 + 1) * 64 + n];
    const float w2 = Ws[(d4 * 4 + 2) * 64 + n];
    const float w3 = Ws[(d4 * 4 + 3) * 64 + n];
#pragma unroll
    for (int i = 0; i < 8; ++i) {
      f32x4 x = X4[(size_t)(kbase + i) * 16 + d4];
      acc[i] += x[0] * w0 + x[1] * w1 + x[2] * w2 + x[3] * w3;
    }
  }

  const int kb = kbase >> 5, kq = (kbase >> 3) & 3;
  const int nb = n >> 4, ln = n & 15;
  const int slot = ((kb * 4 + nb) * 4 + kq) * 16 + ln;
  bf16x8 v;
#pragma unroll
  for (int i = 0; i < 8; ++i) v[i] = (__bf16)acc[i];
  ((bf16x8*)Tsw)[slot] = v;
}

// ---------------------------------------------------------------------------
// Kernel B (REWRITTEN): P[half] = A_hat[:, half] @ T[half, :]
// LDS-staged A path replacing the scattered register-direct loads:
//   - per step (BK=128) each thread issues 8 coalesced nontemporal f32x4
//     loads (wave reads two contiguous 512B row segments per instruction)
//   - fp32->bf16 convert in-register, ds_write_b64 into XOR-swizzled LDS
//     tile [64][128] bf16 (slot16 ^= row&7): bank-optimal b128 frag reads
//   - T14 schedule: issue loads at top of step, compute current buffer,
//     convert+write other buffer, ONE barrier per step (double-buffered)
//   - B fragments register-direct from Tsw (L2-hot), 1-ahead rotating
//     prefetch across the whole K range
// split-K=2 -> 512 blocks = 2 independent blocks/CU (staggered barriers
// keep the CU memory pipe busy).
// ---------------------------------------------------------------------------
constexpr int BM = 64;
constexpr int BK = 128;
constexpr int STEPS = (kN / 2) / BK;   // 64
constexpr int AB_BYTES = BM * BK * 2;  // 16 KB per LDS buffer

__global__ __launch_bounds__(256, 2) void agg_gemm_kernel(
    const float* __restrict__ A, const __bf16* __restrict__ Tsw,
    float* __restrict__ P) {
  __shared__ __align__(16) char As[2][AB_BYTES];

  const int tid  = threadIdx.x;
  const int lane = tid & 63;
  const int wave = tid >> 6;
  const int quad = lane >> 4;
  const int ln   = lane & 15;

  const int half    = blockIdx.x & 1;
  const int rowBase = (blockIdx.x >> 1) * BM;
  const int kStart  = half * (kN / 2);

  // ---- staging mapping: thread covers rows p*8+wr (p=0..7), 16B col wc4 ----
  const int wr  = tid >> 5;   // 0..7
  const int wc4 = tid & 31;   // f32x4 column
  const float* aptr = A + (size_t)(rowBase + wr) * kN + kStart + wc4 * 4;
  // LDS byte for (row=p*8+wr, col4=wc4), swizzled; row&7 == wr
  const int wbyte0 = wr * 256 + ((((wc4 >> 1) << 4) ^ (wr << 4))) + ((wc4 & 1) << 3);

  // ---- fragment read mapping: lane -> A[frow][kk*32 + quad*8 + j] ----
  const int frow  = wave * 16 + ln;
  const int fbase = frow * 256;
  const int fxor  = (ln & 7) << 4;

  // ---- B fragment base (pre-swizzled Tsw) ----
  const bf16x8* bbase = (const bf16x8*)Tsw + (size_t)(kStart >> 5) * 256 + lane;

  f32x4 acc[4] = {};
  f32x4 stage[8];
  bf16x8 bb[2][4];

  // prologue: stage step 0 into As[0]
#pragma unroll
  for (int p = 0; p < 8; ++p)
    stage[p] = __builtin_nontemporal_load((const f32x4*)(aptr + (size_t)p * 8 * kN));
#pragma unroll
  for (int p = 0; p < 8; ++p) {
    bf16x4 v;
#pragma unroll
    for (int j = 0; j < 4; ++j) v[j] = (__bf16)stage[p][j];
    *(bf16x4*)&As[0][wbyte0 + p * 2048] = v;
  }
  __syncthreads();

  // preload B fragments for g=0
#pragma unroll
  for (int nb = 0; nb < 4; ++nb) bb[0][nb] = bbase[nb * 64];

  for (int s = 0; s < STEPS; ++s) {
    const bool more = (s + 1 < STEPS);

    // issue next A tile EARLY (latency hides under this step's compute)
    if (more) {
      const float* ap = aptr + (size_t)(s + 1) * BK;
#pragma unroll
      for (int p = 0; p < 8; ++p)
        stage[p] = __builtin_nontemporal_load((const f32x4*)(ap + (size_t)p * 8 * kN));
    }

    const char* Ab = As[s & 1];
#pragma unroll
    for (int kk = 0; kk < 4; ++kk) {
      const int c = kk & 1;
      // rotating 1-ahead B prefetch (linear in global 32-k index g)
      int gn = s * 4 + kk + 1;
      if (gn > 4 * STEPS - 1) gn = 4 * STEPS - 1;
#pragma unroll
      for (int nb = 0; nb < 4; ++nb)
        bb[c ^ 1][nb] = bbase[(size_t)gn * 256 + nb * 64];

      const bf16x8 af =
          *(const bf16x8*)(Ab + fbase + ((((kk * 4 + quad) << 4) ^ fxor)));
      acc[0] = __builtin_amdgcn_mfma_f32_16x16x32_bf16(af, bb[c][0], acc[0], 0, 0, 0);
      acc[1] = __builtin_amdgcn_mfma_f32_16x16x32_bf16(af, bb[c][1], acc[1], 0, 0, 0);
      acc[2] = __builtin_amdgcn_mfma_f32_16x16x32_bf16(af, bb[c][2], acc[2], 0, 0, 0);
      acc[3] = __builtin_amdgcn_mfma_f32_16x16x32_bf16(af, bb[c][3], acc[3], 0, 0, 0);
    }

    // convert + write next buffer LATE
    if (more) {
      char* Aw = As[(s + 1) & 1];
#pragma unroll
      for (int p = 0; p < 8; ++p) {
        bf16x4 v;
#pragma unroll
        for (int j = 0; j < 4; ++j) v[j] = (__bf16)stage[p][j];
        *(bf16x4*)&Aw[wbyte0 + p * 2048] = v;
      }
    }
    __syncthreads();
  }

  // write fp32 partial tile: C/D layout col=lane&15, row=quad*4+reg
  float* Pout = P + (size_t)half * ((size_t)kN * kD);
#pragma unroll
  for (int nb = 0; nb < 4; ++nb) {
#pragma unroll
    for (int r = 0; r < 4; ++r) {
      const int row = rowBase + wave * 16 + quad * 4 + r;
      const int col = nb * 16 + ln;
      Pout[(size_t)row * kD + col] = acc[nb][r];
    }
  }
}

// ---------------------------------------------------------------------------
// Kernel C (UNCHANGED): out = w * relu(P0 + P1) + (1 - w) * X
// ---------------------------------------------------------------------------
__global__ __launch_bounds__(256) void combine_kernel(
    const float* __restrict__ P, const float* __restrict__ X,
    const float* __restrict__ w, float* __restrict__ out) {
  const int e4 = blockIdx.x * 256 + threadIdx.x; // float4 index
  const f32x4 p0 = ((const f32x4*)P)[e4];
  const f32x4 p1 = ((const f32x4*)(P + (size_t)kN * kD))[e4];
  const f32x4 x = ((const f32x4*)X)[e4];
  const float wr = w[e4 >> 4];
  f32x4 o;
#pragma unroll
  for (int j = 0; j < 4; ++j) {
    float s = p0[j] + p1[j];
    s = s > 0.f ? s : 0.f;
    o[j] = wr * s + (1.f - wr) * x[j];
  }
  ((f32x4*)out)[e4] = o;
}

// ---------------------------------------------------------------------------
extern "C" void kernel_launch(void* const* d_in, const int* in_sizes, int n_in,
                              void* d_out, int out_size, void* d_ws, size_t ws_size,
                              hipStream_t stream) {
  const float* X = (const float*)d_in[0];     // [16384, 64]
  const float* A = (const float*)d_in[1];     // [16384, 16384]
  const float* w = (const float*)d_in[2];     // [16384]
  const float* W = (const float*)d_in[3];     // [64, 64]
  float* out = (float*)d_out;

  // ws layout: [0, 2MB) Tsw (bf16 swizzled), [2MB, 10MB) split-K partials
  __bf16* Tsw = (__bf16*)d_ws;
  float* P = (float*)((char*)d_ws + (size_t)2 * 1024 * 1024);

  xw_swizzle_kernel<<<512, 256, 0, stream>>>(X, W, Tsw);
  agg_gemm_kernel<<<512, 256, 0, stream>>>(A, Tsw, P);
  combine_kernel<<<1024, 256, 0, stream>>>(P, X, w, out);
}